// Round 1
// baseline (8375.750 us; speedup 1.0000x reference)
//
#include <hip/hip_runtime.h>
#include <hip/hip_bf16.h>

typedef unsigned short u16;
typedef __attribute__((ext_vector_type(4))) float f32x4;
typedef __attribute__((ext_vector_type(8))) __bf16 bf16x8;

#define DEV static __device__ __forceinline__

// ---------- helpers ----------
DEV float b2f(u16 v) { return __uint_as_float(((unsigned)v) << 16); }

DEV u16 f2b(float f) {  // round-to-nearest-even f32 -> bf16 bits
  unsigned u = __float_as_uint(f);
  return (u16)((u + 0x7fffu + ((u >> 16) & 1u)) >> 16);
}

DEV void gload16(const void* g, void* l) {
  // async global->LDS, 16B per lane; LDS dest is wave-uniform base + lane*16
  __builtin_amdgcn_global_load_lds(
      (__attribute__((address_space(1))) void*)g,
      (__attribute__((address_space(3))) void*)l, 16, 0, 0);
}

DEV float wave_sum(float v) {
  #pragma unroll
  for (int o = 32; o; o >>= 1) v += __shfl_xor(v, o, 64);
  return v;
}
DEV float wave_max(float v) {
  #pragma unroll
  for (int o = 32; o; o >>= 1) v = fmaxf(v, __shfl_xor(v, o, 64));
  return v;
}

// ---------- embeddings + LayerNorm (f32 out) ----------
__global__ __launch_bounds__(256)
void embed_ln_k(const int* __restrict__ ids, const int* __restrict__ tts,
                const float* __restrict__ we, const float* __restrict__ pe,
                const float* __restrict__ te, const float* __restrict__ g,
                const float* __restrict__ bb, float* __restrict__ x) {
  const int t = blockIdx.x;          // 0..4095 token index
  const int pos = t & 511;
  const int tid = threadIdx.x, lane = tid & 63, w = tid >> 6;
  const int id = ids[t], tt = tts[t];
  __shared__ float red[8];
  float e[3];
  #pragma unroll
  for (int k = 0; k < 3; k++) {
    int d = tid + k * 256;
    e[k] = we[(size_t)id * 768 + d] + pe[(size_t)pos * 768 + d] + te[(size_t)tt * 768 + d];
  }
  float s = wave_sum(e[0] + e[1] + e[2]);
  if (lane == 0) red[w] = s;
  __syncthreads();
  const float mean = (red[0] + red[1] + red[2] + red[3]) * (1.f / 768.f);
  float v2 = 0.f;
  #pragma unroll
  for (int k = 0; k < 3; k++) { float d = e[k] - mean; v2 += d * d; }
  v2 = wave_sum(v2);
  if (lane == 0) red[4 + w] = v2;
  __syncthreads();
  const float var = (red[4] + red[5] + red[6] + red[7]) * (1.f / 768.f);
  const float rstd = rsqrtf(var + 1e-5f);
  #pragma unroll
  for (int k = 0; k < 3; k++) {
    int d = tid + k * 256;
    x[(size_t)t * 768 + d] = (e[k] - mean) * rstd * g[d] + bb[d];
  }
}

// ---------- LayerNorm f32 -> bf16 ----------
__global__ __launch_bounds__(256)
void ln_k(const float* __restrict__ xin, const float* __restrict__ g,
          const float* __restrict__ bb, u16* __restrict__ out) {
  const int t = blockIdx.x;
  const int tid = threadIdx.x, lane = tid & 63, w = tid >> 6;
  __shared__ float red[8];
  float e[3];
  #pragma unroll
  for (int k = 0; k < 3; k++) e[k] = xin[(size_t)t * 768 + tid + k * 256];
  float s = wave_sum(e[0] + e[1] + e[2]);
  if (lane == 0) red[w] = s;
  __syncthreads();
  const float mean = (red[0] + red[1] + red[2] + red[3]) * (1.f / 768.f);
  float v2 = 0.f;
  #pragma unroll
  for (int k = 0; k < 3; k++) { float d = e[k] - mean; v2 += d * d; }
  v2 = wave_sum(v2);
  if (lane == 0) red[4 + w] = v2;
  __syncthreads();
  const float var = (red[4] + red[5] + red[6] + red[7]) * (1.f / 768.f);
  const float rstd = rsqrtf(var + 1e-5f);
  #pragma unroll
  for (int k = 0; k < 3; k++) {
    int d = tid + k * 256;
    out[(size_t)t * 768 + d] = f2b((e[k] - mean) * rstd * g[d] + bb[d]);
  }
}

// ---------- f32 -> bf16 cast (4 elems/thread) ----------
__global__ __launch_bounds__(256)
void cast_k(const float* __restrict__ xin, u16* __restrict__ out) {
  const int i = blockIdx.x * 256 + threadIdx.x;
  float4 v = ((const float4*)xin)[i];
  uint2 o;
  o.x = (unsigned)f2b(v.x) | ((unsigned)f2b(v.y) << 16);
  o.y = (unsigned)f2b(v.z) | ((unsigned)f2b(v.w) << 16);
  ((uint2*)out)[i] = o;
}

// ---------- GEMM: C[M,N] = epi(A_bf16[M,K] @ B_f32 + bias) ----------
// BT=false: B is [K,N] row-major f32. BT=true: B is [N,K] row-major f32 (B^T).
// EPI: 0 = store bf16; 1 = GELU -> bf16; 2 = resid_f32 + val -> f32; 3 = f32 store with N-guard.
template <int EPI, bool BT>
__global__ __launch_bounds__(256)
void gemm_k(const u16* __restrict__ A, const float* __restrict__ Bm,
            const float* __restrict__ bias, const float* __restrict__ resid,
            void* __restrict__ Cptr, int Mdim, int Ndim, int Kdim) {
  __shared__ __align__(16) u16 As[128 * 32];  // [row][k], k contiguous
  __shared__ __align__(16) u16 Bs[128 * 32];  // [col][k], k contiguous
  const int tid = threadIdx.x, lane = tid & 63, w = tid >> 6;
  const int wr = w >> 1, wc = w & 1, fr = lane & 15, fq = lane >> 4;
  const int n0 = blockIdx.x * 128, m0 = blockIdx.y * 128;
  f32x4 acc[4][4] = {};
  const int arow = w * 16 + (lane >> 2), akk = (lane & 3) * 8;

  for (int k0 = 0; k0 < Kdim; k0 += 32) {
    // --- stage A (bf16) via async global->LDS, 2 issues/wave ---
    gload16(A + (size_t)(m0 + arow) * Kdim + k0 + akk, As + w * 512);
    gload16(A + (size_t)(m0 + 64 + arow) * Kdim + k0 + akk, As + 2048 + w * 512);
    // --- stage B (f32 -> bf16 convert, transposed into [col][k]) ---
    if (BT) {
      const int n = tid >> 1, kh = (tid & 1) * 16;
      const bool ok = (n0 + n) < Ndim;
      const float* src = Bm + (size_t)(n0 + n) * Kdim + k0 + kh;
      unsigned pk[8];
      #pragma unroll
      for (int q = 0; q < 4; q++) {
        float4 t = ok ? ((const float4*)src)[q] : make_float4(0.f, 0.f, 0.f, 0.f);
        pk[q * 2]     = (unsigned)f2b(t.x) | ((unsigned)f2b(t.y) << 16);
        pk[q * 2 + 1] = (unsigned)f2b(t.z) | ((unsigned)f2b(t.w) << 16);
      }
      int4* dst = (int4*)(Bs + n * 32 + kh);
      dst[0] = make_int4((int)pk[0], (int)pk[1], (int)pk[2], (int)pk[3]);
      dst[1] = make_int4((int)pk[4], (int)pk[5], (int)pk[6], (int)pk[7]);
    } else {
      const int n = tid & 127, kh = (tid >> 7) * 16;
      const float* src = Bm + (size_t)(k0 + kh) * Ndim + n0 + n;
      unsigned pk[8];
      #pragma unroll
      for (int q = 0; q < 8; q++) {
        float a0 = src[(size_t)(2 * q) * Ndim];
        float a1 = src[(size_t)(2 * q + 1) * Ndim];
        pk[q] = (unsigned)f2b(a0) | ((unsigned)f2b(a1) << 16);
      }
      int4* dst = (int4*)(Bs + n * 32 + kh);
      dst[0] = make_int4((int)pk[0], (int)pk[1], (int)pk[2], (int)pk[3]);
      dst[1] = make_int4((int)pk[4], (int)pk[5], (int)pk[6], (int)pk[7]);
    }
    __syncthreads();
    // --- fragments + MFMA ---
    bf16x8 af[4], bfv[4];
    #pragma unroll
    for (int m = 0; m < 4; m++)
      af[m] = *(const bf16x8*)(As + (wr * 64 + m * 16 + fr) * 32 + fq * 8);
    #pragma unroll
    for (int n = 0; n < 4; n++)
      bfv[n] = *(const bf16x8*)(Bs + (wc * 64 + n * 16 + fr) * 32 + fq * 8);
    #pragma unroll
    for (int m = 0; m < 4; m++)
      #pragma unroll
      for (int n = 0; n < 4; n++)
        acc[m][n] = __builtin_amdgcn_mfma_f32_16x16x32_bf16(af[m], bfv[n], acc[m][n], 0, 0, 0);
    __syncthreads();
  }

  // --- epilogue ---
  #pragma unroll
  for (int m = 0; m < 4; m++) {
    const int row = m0 + wr * 64 + m * 16 + fq * 4;
    #pragma unroll
    for (int n = 0; n < 4; n++) {
      const int col = n0 + wc * 64 + n * 16 + fr;
      if (EPI == 3 && col >= Ndim) continue;
      const float bv = (bias != nullptr) ? bias[col] : 0.f;
      #pragma unroll
      for (int r = 0; r < 4; r++) {
        float v = acc[m][n][r] + bv;
        const size_t idx = (size_t)(row + r) * Ndim + col;
        if (EPI == 0) {
          ((u16*)Cptr)[idx] = f2b(v);
        } else if (EPI == 1) {
          float t = v;
          float gl = 0.5f * t * (1.f + tanhf(0.7978845608f * (t + 0.044715f * t * t * t)));
          ((u16*)Cptr)[idx] = f2b(gl);
        } else if (EPI == 2) {
          ((float*)Cptr)[idx] = resid[idx] + v;
        } else {
          ((float*)Cptr)[idx] = v;
        }
      }
    }
  }
}

// ---------- attention (VALU flash-style, exact softmax) ----------
// grid: (T/32, B*H). block 256 = 4 waves; each wave does 8 q-rows.
__global__ __launch_bounds__(256)
void attn_k(const u16* __restrict__ qkv, const float* __restrict__ amask,
            u16* __restrict__ y) {
  __shared__ __align__(16) u16 Ks[512 * 68];  // stride 68 (136B): 8B-aligned rows, ~4-way banks
  __shared__ __align__(16) u16 Qs[32 * 68];
  __shared__ u16 pb[4 * 512];                 // per-wave softmax weights (bf16)
  const int tid = threadIdx.x, lane = tid & 63, w = tid >> 6;
  const int bh = blockIdx.y, b = bh / 12, hh = bh % 12;
  const int q0 = blockIdx.x * 32;
  const u16* qb = qkv + (size_t)(b * 512) * 2304 + hh * 64;
  const u16* kb = qb + 768;
  const u16* vb = qb + 1536;

  // stage K (512x64) and Q chunk (32x64)
  for (int c = tid; c < 4096; c += 256) {
    int r = c >> 3, ch = c & 7;
    int4 vd = *(const int4*)(kb + (size_t)r * 2304 + ch * 8);
    uint2* dst = (uint2*)(Ks + r * 68 + ch * 8);
    dst[0] = make_uint2((unsigned)vd.x, (unsigned)vd.y);
    dst[1] = make_uint2((unsigned)vd.z, (unsigned)vd.w);
  }
  {
    int c = tid;  // exactly 256 chunks
    int r = c >> 3, ch = c & 7;
    int4 vd = *(const int4*)(qb + (size_t)(q0 + r) * 2304 + ch * 8);
    uint2* dst = (uint2*)(Qs + r * 68 + ch * 8);
    dst[0] = make_uint2((unsigned)vd.x, (unsigned)vd.y);
    dst[1] = make_uint2((unsigned)vd.z, (unsigned)vd.w);
  }
  __syncthreads();

  const float scale = 0.125f;  // 1/sqrt(64)
  float mbias[8];
  #pragma unroll
  for (int m = 0; m < 8; m++)
    mbias[m] = (1.0f - amask[b * 512 + m * 64 + lane]) * -10000.0f;

  for (int rr = 0; rr < 8; rr++) {
    const int r = w * 8 + rr;  // local q row 0..31
    float s[8];
    #pragma unroll
    for (int m = 0; m < 8; m++) s[m] = 0.f;
    for (int d = 0; d < 64; d += 4) {
      uint2 qd = *(const uint2*)(Qs + r * 68 + d);  // broadcast
      float q0f = b2f((u16)qd.x), q1f = b2f((u16)(qd.x >> 16));
      float q2f = b2f((u16)qd.y), q3f = b2f((u16)(qd.y >> 16));
      #pragma unroll
      for (int m = 0; m < 8; m++) {
        uint2 kd = *(const uint2*)(Ks + (m * 64 + lane) * 68 + d);
        s[m] += q0f * b2f((u16)kd.x) + q1f * b2f((u16)(kd.x >> 16)) +
                q2f * b2f((u16)kd.y) + q3f * b2f((u16)(kd.y >> 16));
      }
    }
    // softmax over 512 (8 regs x 64 lanes)
    float mx = -3.0e38f;
    #pragma unroll
    for (int m = 0; m < 8; m++) { s[m] = s[m] * scale + mbias[m]; mx = fmaxf(mx, s[m]); }
    mx = wave_max(mx);
    float p[8], sum = 0.f;
    #pragma unroll
    for (int m = 0; m < 8; m++) { p[m] = __expf(s[m] - mx); sum += p[m]; }
    sum = wave_sum(sum);
    #pragma unroll
    for (int m = 0; m < 8; m++) pb[w * 512 + m * 64 + lane] = f2b(p[m]);
    asm volatile("s_waitcnt lgkmcnt(0)" ::: "memory");
    // PV: half-wave per j, lane owns a d-pair
    const int jj = lane >> 5, dp = (lane & 31) * 2;
    float y0 = 0.f, y1 = 0.f;
    #pragma unroll 4
    for (int j = 0; j < 512; j += 2) {
      int jr = j + jj;
      float pj = b2f(pb[w * 512 + jr]);
      unsigned vd = *(const unsigned*)(vb + (size_t)jr * 2304 + dp);
      y0 += pj * b2f((u16)vd);
      y1 += pj * b2f((u16)(vd >> 16));
    }
    y0 += __shfl_xor(y0, 32, 64);
    y1 += __shfl_xor(y1, 32, 64);
    if (lane < 32) {
      float inv = 1.0f / sum;
      unsigned o = (unsigned)f2b(y0 * inv) | ((unsigned)f2b(y1 * inv) << 16);
      *(unsigned*)(y + (size_t)(b * 512 + q0 + r) * 768 + hh * 64 + dp) = o;
    }
  }
}

// ---------- launch ----------
extern "C" void kernel_launch(void* const* d_in, const int* in_sizes, int n_in,
                              void* d_out, int out_size, void* d_ws, size_t ws_size,
                              hipStream_t stream) {
  (void)in_sizes; (void)n_in; (void)out_size; (void)ws_size;
  const int*   ids  = (const int*)d_in[0];
  const int*   tts  = (const int*)d_in[1];
  const float* am   = (const float*)d_in[2];
  const float* we   = (const float*)d_in[3];
  const float* pe   = (const float*)d_in[4];
  const float* te   = (const float*)d_in[5];
  const float* eg   = (const float*)d_in[6];
  const float* eb   = (const float*)d_in[7];
  const float* l1g  = (const float*)d_in[8];
  const float* l1b  = (const float*)d_in[9];
  const float* wqkv = (const float*)d_in[10];
  const float* bqkv = (const float*)d_in[11];
  const float* wprj = (const float*)d_in[12];
  const float* bprj = (const float*)d_in[13];
  const float* l2g  = (const float*)d_in[14];
  const float* l2b  = (const float*)d_in[15];
  const float* wfc  = (const float*)d_in[16];
  const float* bfc  = (const float*)d_in[17];
  const float* wfc2 = (const float*)d_in[18];
  const float* bfc2 = (const float*)d_in[19];

  char* ws = (char*)d_ws;
  float* x  = (float*)ws;                       // 12,582,912 B
  u16*  h   = (u16*)(ws + 12582912);            //  6,291,456 B
  u16*  qkv = (u16*)(ws + 18874368);            // 18,874,368 B
  u16*  y   = (u16*)(ws + 37748736);            //  6,291,456 B
  u16*  fc  = (u16*)(ws + 18874368);            // aliases qkv+y (dead by then), 25,165,824 B

  embed_ln_k<<<4096, 256, 0, stream>>>(ids, tts, we, pe, te, eg, eb, x);

  for (int l = 0; l < 12; l++) {
    ln_k<<<4096, 256, 0, stream>>>(x, l1g + l * 768, l1b + l * 768, h);
    gemm_k<0, false><<<dim3(18, 32), 256, 0, stream>>>(
        h, wqkv + (size_t)l * 768 * 2304, bqkv + l * 2304, nullptr, qkv, 4096, 2304, 768);
    attn_k<<<dim3(16, 96), 256, 0, stream>>>(qkv, am, y);
    gemm_k<2, false><<<dim3(6, 32), 256, 0, stream>>>(
        y, wprj + (size_t)l * 768 * 768, bprj + l * 768, x, x, 4096, 768, 768);
    ln_k<<<4096, 256, 0, stream>>>(x, l2g + l * 768, l2b + l * 768, h);
    gemm_k<1, false><<<dim3(24, 32), 256, 0, stream>>>(
        h, wfc + (size_t)l * 768 * 3072, bfc + l * 3072, nullptr, fc, 4096, 3072, 768);
    gemm_k<2, false><<<dim3(6, 32), 256, 0, stream>>>(
        fc, wfc2 + (size_t)l * 3072 * 768, bfc2 + l * 768, x, x, 4096, 768, 3072);
  }

  cast_k<<<3072, 256, 0, stream>>>(x, h);
  gemm_k<3, true><<<dim3(239, 32), 256, 0, stream>>>(
      h, we, nullptr, nullptr, d_out, 4096, 30522, 768);
}

// Round 2
// 7387.600 us; speedup vs baseline: 1.1338x; 1.1338x over previous
//
#include <hip/hip_runtime.h>
#include <hip/hip_bf16.h>

typedef unsigned short u16;
typedef __attribute__((ext_vector_type(4))) float f32x4;
typedef __attribute__((ext_vector_type(8))) __bf16 bf16x8;

#define DEV static __device__ __forceinline__

// ---------- helpers ----------
DEV float b2f(u16 v) { return __uint_as_float(((unsigned)v) << 16); }

DEV u16 f2b(float f) {  // round-to-nearest-even f32 -> bf16 bits
  unsigned u = __float_as_uint(f);
  return (u16)((u + 0x7fffu + ((u >> 16) & 1u)) >> 16);
}

DEV void gload16(const void* g, void* l) {
  // async global->LDS, 16B per lane; LDS dest is wave-uniform base + lane*16
  __builtin_amdgcn_global_load_lds(
      (__attribute__((address_space(1))) void*)g,
      (__attribute__((address_space(3))) void*)l, 16, 0, 0);
}

DEV float wave_sum(float v) {
  #pragma unroll
  for (int o = 32; o; o >>= 1) v += __shfl_xor(v, o, 64);
  return v;
}
DEV float wave_max(float v) {
  #pragma unroll
  for (int o = 32; o; o >>= 1) v = fmaxf(v, __shfl_xor(v, o, 64));
  return v;
}

// ---------- embeddings + LayerNorm (f32 out) ----------
__global__ __launch_bounds__(256)
void embed_ln_k(const int* __restrict__ ids, const int* __restrict__ tts,
                const float* __restrict__ we, const float* __restrict__ pe,
                const float* __restrict__ te, const float* __restrict__ g,
                const float* __restrict__ bb, float* __restrict__ x) {
  const int t = blockIdx.x;          // 0..4095 token index
  const int pos = t & 511;
  const int tid = threadIdx.x, lane = tid & 63, w = tid >> 6;
  const int id = ids[t], tt = tts[t];
  __shared__ float red[8];
  float e[3];
  #pragma unroll
  for (int k = 0; k < 3; k++) {
    int d = tid + k * 256;
    e[k] = we[(size_t)id * 768 + d] + pe[(size_t)pos * 768 + d] + te[(size_t)tt * 768 + d];
  }
  float s = wave_sum(e[0] + e[1] + e[2]);
  if (lane == 0) red[w] = s;
  __syncthreads();
  const float mean = (red[0] + red[1] + red[2] + red[3]) * (1.f / 768.f);
  float v2 = 0.f;
  #pragma unroll
  for (int k = 0; k < 3; k++) { float d = e[k] - mean; v2 += d * d; }
  v2 = wave_sum(v2);
  if (lane == 0) red[4 + w] = v2;
  __syncthreads();
  const float var = (red[4] + red[5] + red[6] + red[7]) * (1.f / 768.f);
  const float rstd = rsqrtf(var + 1e-5f);
  #pragma unroll
  for (int k = 0; k < 3; k++) {
    int d = tid + k * 256;
    x[(size_t)t * 768 + d] = (e[k] - mean) * rstd * g[d] + bb[d];
  }
}

// ---------- LayerNorm f32 -> bf16 ----------
__global__ __launch_bounds__(256)
void ln_k(const float* __restrict__ xin, const float* __restrict__ g,
          const float* __restrict__ bb, u16* __restrict__ out) {
  const int t = blockIdx.x;
  const int tid = threadIdx.x, lane = tid & 63, w = tid >> 6;
  __shared__ float red[8];
  float e[3];
  #pragma unroll
  for (int k = 0; k < 3; k++) e[k] = xin[(size_t)t * 768 + tid + k * 256];
  float s = wave_sum(e[0] + e[1] + e[2]);
  if (lane == 0) red[w] = s;
  __syncthreads();
  const float mean = (red[0] + red[1] + red[2] + red[3]) * (1.f / 768.f);
  float v2 = 0.f;
  #pragma unroll
  for (int k = 0; k < 3; k++) { float d = e[k] - mean; v2 += d * d; }
  v2 = wave_sum(v2);
  if (lane == 0) red[4 + w] = v2;
  __syncthreads();
  const float var = (red[4] + red[5] + red[6] + red[7]) * (1.f / 768.f);
  const float rstd = rsqrtf(var + 1e-5f);
  #pragma unroll
  for (int k = 0; k < 3; k++) {
    int d = tid + k * 256;
    out[(size_t)t * 768 + d] = f2b((e[k] - mean) * rstd * g[d] + bb[d]);
  }
}

// ---------- f32 -> bf16 cast (4 elems/thread) ----------
__global__ __launch_bounds__(256)
void cast_k(const float* __restrict__ xin, u16* __restrict__ out) {
  const int i = blockIdx.x * 256 + threadIdx.x;
  float4 v = ((const float4*)xin)[i];
  uint2 o;
  o.x = (unsigned)f2b(v.x) | ((unsigned)f2b(v.y) << 16);
  o.y = (unsigned)f2b(v.z) | ((unsigned)f2b(v.w) << 16);
  ((uint2*)out)[i] = o;
}

// ---------- word_emb f32[30522,768] -> bf16[30592,768], pad rows zeroed ----------
__global__ __launch_bounds__(256)
void wecast_k(const float* __restrict__ we, u16* __restrict__ out) {
  const int i = blockIdx.x * 256 + threadIdx.x;  // 8-elem chunk, 2,936,832 total
  const int row = i / 96, c8 = i % 96;
  uint2 o0 = make_uint2(0u, 0u), o1 = make_uint2(0u, 0u);
  if (row < 30522) {
    const float* src = we + (size_t)row * 768 + c8 * 8;
    float4 a = ((const float4*)src)[0];
    float4 b = ((const float4*)src)[1];
    o0.x = (unsigned)f2b(a.x) | ((unsigned)f2b(a.y) << 16);
    o0.y = (unsigned)f2b(a.z) | ((unsigned)f2b(a.w) << 16);
    o1.x = (unsigned)f2b(b.x) | ((unsigned)f2b(b.y) << 16);
    o1.y = (unsigned)f2b(b.z) | ((unsigned)f2b(b.w) << 16);
  }
  uint2* dst = (uint2*)(out + (size_t)i * 8);
  dst[0] = o0;
  dst[1] = o1;
}

// ---------- transpose-convert: W f32[K,N] -> Wt bf16[N,K] ----------
// grid (N/64, K/64), block 256
__global__ __launch_bounds__(256)
void tconv_k(const float* __restrict__ W, u16* __restrict__ Wt, int K, int N) {
  __shared__ u16 t[64][65];
  const int tid = threadIdx.x;
  const int n0 = blockIdx.x * 64, k0 = blockIdx.y * 64;
  const int kl = tid >> 4, nl4 = (tid & 15) * 4;
  #pragma unroll
  for (int i = 0; i < 4; i++) {
    float4 v = *(const float4*)(W + (size_t)(k0 + kl + i * 16) * N + n0 + nl4);
    t[nl4 + 0][kl + i * 16] = f2b(v.x);
    t[nl4 + 1][kl + i * 16] = f2b(v.y);
    t[nl4 + 2][kl + i * 16] = f2b(v.z);
    t[nl4 + 3][kl + i * 16] = f2b(v.w);
  }
  __syncthreads();
  const int nl = tid >> 2, kc = (tid & 3) * 16;
  unsigned wd[8];
  #pragma unroll
  for (int j = 0; j < 8; j++)
    wd[j] = (unsigned)t[nl][kc + 2 * j] | ((unsigned)t[nl][kc + 2 * j + 1] << 16);
  int4* dst = (int4*)(Wt + (size_t)(n0 + nl) * K + k0 + kc);
  dst[0] = make_int4((int)wd[0], (int)wd[1], (int)wd[2], (int)wd[3]);
  dst[1] = make_int4((int)wd[4], (int)wd[5], (int)wd[6], (int)wd[7]);
}

// ---------- GEMM: C[M,N] = epi(A_bf16[M,K] @ B_bf16[N,K]^T + bias) ----------
// A: [M,K] bf16 row-major. B: [N,K] bf16 row-major (i.e. column n of C has
// weight row n). Both staged via global_load_lds width-16 (m97 structure).
// EPI: 0 = store bf16; 1 = GELU -> bf16; 2 = resid_f32 + val -> f32; 3 = f32 store with N-guard.
template <int EPI>
__global__ __launch_bounds__(256)
void gemm_k(const u16* __restrict__ A, const u16* __restrict__ B,
            const float* __restrict__ bias, const float* __restrict__ resid,
            void* __restrict__ Cptr, int Mdim, int Ndim, int Kdim) {
  __shared__ __align__(16) u16 As[128 * 32];  // [row][k], k contiguous
  __shared__ __align__(16) u16 Bs[128 * 32];  // [col][k], k contiguous
  const int tid = threadIdx.x, lane = tid & 63, w = tid >> 6;
  const int wr = w >> 1, wc = w & 1, fr = lane & 15, fq = lane >> 4;
  const int n0 = blockIdx.x * 128, m0 = blockIdx.y * 128;
  f32x4 acc[4][4] = {};
  const int arow = w * 16 + (lane >> 2), akk = (lane & 3) * 8;

  for (int k0 = 0; k0 < Kdim; k0 += 32) {
    gload16(A + (size_t)(m0 + arow) * Kdim + k0 + akk, As + w * 512);
    gload16(A + (size_t)(m0 + 64 + arow) * Kdim + k0 + akk, As + 2048 + w * 512);
    gload16(B + (size_t)(n0 + arow) * Kdim + k0 + akk, Bs + w * 512);
    gload16(B + (size_t)(n0 + 64 + arow) * Kdim + k0 + akk, Bs + 2048 + w * 512);
    __syncthreads();
    bf16x8 af[4], bfv[4];
    #pragma unroll
    for (int m = 0; m < 4; m++)
      af[m] = *(const bf16x8*)(As + (wr * 64 + m * 16 + fr) * 32 + fq * 8);
    #pragma unroll
    for (int n = 0; n < 4; n++)
      bfv[n] = *(const bf16x8*)(Bs + (wc * 64 + n * 16 + fr) * 32 + fq * 8);
    #pragma unroll
    for (int m = 0; m < 4; m++)
      #pragma unroll
      for (int n = 0; n < 4; n++)
        acc[m][n] = __builtin_amdgcn_mfma_f32_16x16x32_bf16(af[m], bfv[n], acc[m][n], 0, 0, 0);
    __syncthreads();
  }

  #pragma unroll
  for (int m = 0; m < 4; m++) {
    const int row = m0 + wr * 64 + m * 16 + fq * 4;
    #pragma unroll
    for (int n = 0; n < 4; n++) {
      const int col = n0 + wc * 64 + n * 16 + fr;
      if (EPI == 3 && col >= Ndim) continue;
      const float bv = (bias != nullptr) ? bias[col] : 0.f;
      #pragma unroll
      for (int r = 0; r < 4; r++) {
        float v = acc[m][n][r] + bv;
        const size_t idx = (size_t)(row + r) * Ndim + col;
        if (EPI == 0) {
          ((u16*)Cptr)[idx] = f2b(v);
        } else if (EPI == 1) {
          float t = v;
          float gl = 0.5f * t * (1.f + tanhf(0.7978845608f * (t + 0.044715f * t * t * t)));
          ((u16*)Cptr)[idx] = f2b(gl);
        } else if (EPI == 2) {
          ((float*)Cptr)[idx] = resid[idx] + v;
        } else {
          ((float*)Cptr)[idx] = v;
        }
      }
    }
  }
}

// ---------- attention (VALU flash-style, exact softmax) ----------
// grid: (T/32, B*H). block 256 = 4 waves; each wave does 8 q-rows.
__global__ __launch_bounds__(256)
void attn_k(const u16* __restrict__ qkv, const float* __restrict__ amask,
            u16* __restrict__ y) {
  __shared__ __align__(16) u16 Ks[512 * 68];  // stride 68 (136B): 8B-aligned rows, ~4-way banks
  __shared__ __align__(16) u16 Qs[32 * 68];
  __shared__ u16 pb[4 * 512];                 // per-wave softmax weights (bf16)
  const int tid = threadIdx.x, lane = tid & 63, w = tid >> 6;
  const int bh = blockIdx.y, b = bh / 12, hh = bh % 12;
  const int q0 = blockIdx.x * 32;
  const u16* qb = qkv + (size_t)(b * 512) * 2304 + hh * 64;
  const u16* kb = qb + 768;
  const u16* vb = qb + 1536;

  for (int c = tid; c < 4096; c += 256) {
    int r = c >> 3, ch = c & 7;
    int4 vd = *(const int4*)(kb + (size_t)r * 2304 + ch * 8);
    uint2* dst = (uint2*)(Ks + r * 68 + ch * 8);
    dst[0] = make_uint2((unsigned)vd.x, (unsigned)vd.y);
    dst[1] = make_uint2((unsigned)vd.z, (unsigned)vd.w);
  }
  {
    int c = tid;
    int r = c >> 3, ch = c & 7;
    int4 vd = *(const int4*)(qb + (size_t)(q0 + r) * 2304 + ch * 8);
    uint2* dst = (uint2*)(Qs + r * 68 + ch * 8);
    dst[0] = make_uint2((unsigned)vd.x, (unsigned)vd.y);
    dst[1] = make_uint2((unsigned)vd.z, (unsigned)vd.w);
  }
  __syncthreads();

  const float scale = 0.125f;  // 1/sqrt(64)
  float mbias[8];
  #pragma unroll
  for (int m = 0; m < 8; m++)
    mbias[m] = (1.0f - amask[b * 512 + m * 64 + lane]) * -10000.0f;

  for (int rr = 0; rr < 8; rr++) {
    const int r = w * 8 + rr;
    float s[8];
    #pragma unroll
    for (int m = 0; m < 8; m++) s[m] = 0.f;
    for (int d = 0; d < 64; d += 4) {
      uint2 qd = *(const uint2*)(Qs + r * 68 + d);
      float q0f = b2f((u16)qd.x), q1f = b2f((u16)(qd.x >> 16));
      float q2f = b2f((u16)qd.y), q3f = b2f((u16)(qd.y >> 16));
      #pragma unroll
      for (int m = 0; m < 8; m++) {
        uint2 kd = *(const uint2*)(Ks + (m * 64 + lane) * 68 + d);
        s[m] += q0f * b2f((u16)kd.x) + q1f * b2f((u16)(kd.x >> 16)) +
                q2f * b2f((u16)kd.y) + q3f * b2f((u16)(kd.y >> 16));
      }
    }
    float mx = -3.0e38f;
    #pragma unroll
    for (int m = 0; m < 8; m++) { s[m] = s[m] * scale + mbias[m]; mx = fmaxf(mx, s[m]); }
    mx = wave_max(mx);
    float p[8], sum = 0.f;
    #pragma unroll
    for (int m = 0; m < 8; m++) { p[m] = __expf(s[m] - mx); sum += p[m]; }
    sum = wave_sum(sum);
    #pragma unroll
    for (int m = 0; m < 8; m++) pb[w * 512 + m * 64 + lane] = f2b(p[m]);
    asm volatile("s_waitcnt lgkmcnt(0)" ::: "memory");
    const int jj = lane >> 5, dp = (lane & 31) * 2;
    float y0 = 0.f, y1 = 0.f;
    #pragma unroll 4
    for (int j = 0; j < 512; j += 2) {
      int jr = j + jj;
      float pj = b2f(pb[w * 512 + jr]);
      unsigned vd = *(const unsigned*)(vb + (size_t)jr * 2304 + dp);
      y0 += pj * b2f((u16)vd);
      y1 += pj * b2f((u16)(vd >> 16));
    }
    y0 += __shfl_xor(y0, 32, 64);
    y1 += __shfl_xor(y1, 32, 64);
    if (lane < 32) {
      float inv = 1.0f / sum;
      unsigned o = (unsigned)f2b(y0 * inv) | ((unsigned)f2b(y1 * inv) << 16);
      *(unsigned*)(y + (size_t)(b * 512 + q0 + r) * 768 + hh * 64 + dp) = o;
    }
  }
}

// ---------- launch ----------
extern "C" void kernel_launch(void* const* d_in, const int* in_sizes, int n_in,
                              void* d_out, int out_size, void* d_ws, size_t ws_size,
                              hipStream_t stream) {
  (void)in_sizes; (void)n_in; (void)out_size; (void)ws_size;
  const int*   ids  = (const int*)d_in[0];
  const int*   tts  = (const int*)d_in[1];
  const float* am   = (const float*)d_in[2];
  const float* we   = (const float*)d_in[3];
  const float* pe   = (const float*)d_in[4];
  const float* te   = (const float*)d_in[5];
  const float* eg   = (const float*)d_in[6];
  const float* eb   = (const float*)d_in[7];
  const float* l1g  = (const float*)d_in[8];
  const float* l1b  = (const float*)d_in[9];
  const float* wqkv = (const float*)d_in[10];
  const float* bqkv = (const float*)d_in[11];
  const float* wprj = (const float*)d_in[12];
  const float* bprj = (const float*)d_in[13];
  const float* l2g  = (const float*)d_in[14];
  const float* l2b  = (const float*)d_in[15];
  const float* wfc  = (const float*)d_in[16];
  const float* bfc  = (const float*)d_in[17];
  const float* wfc2 = (const float*)d_in[18];
  const float* bfc2 = (const float*)d_in[19];

  char* ws = (char*)d_ws;
  float* x   = (float*)ws;                      // 12,582,912 B  activations f32
  u16*  h    = (u16*)(ws + 12582912);           //  6,291,456 B  LN output bf16
  u16*  qkv  = (u16*)(ws + 18874368);           // 18,874,368 B
  u16*  y    = (u16*)(ws + 37748736);           //  6,291,456 B
  u16*  fc   = (u16*)(ws + 18874368);           // aliases qkv+y (dead by then)
  // bf16 weight staging (reused each layer)
  u16*  wqkv_b = (u16*)(ws + 44040192);         //  3,538,944 B  [2304,768]
  u16*  wprj_b = (u16*)(ws + 47579136);         //  1,179,648 B  [768,768]
  u16*  wfc_b  = (u16*)(ws + 48758784);         //  4,718,592 B  [3072,768]
  u16*  wfc2_b = (u16*)(ws + 53477376);         //  4,718,592 B  [768,3072]
  u16*  we_b   = (u16*)(ws + 58195968);         // 46,989,312 B  [30592,768] zero-padded
  // total ws use: 105,185,280 B

  wecast_k<<<11472, 256, 0, stream>>>(we, we_b);
  embed_ln_k<<<4096, 256, 0, stream>>>(ids, tts, we, pe, te, eg, eb, x);

  for (int l = 0; l < 12; l++) {
    tconv_k<<<dim3(36, 12), 256, 0, stream>>>(wqkv + (size_t)l * 768 * 2304, wqkv_b, 768, 2304);
    tconv_k<<<dim3(12, 12), 256, 0, stream>>>(wprj + (size_t)l * 768 * 768,  wprj_b, 768, 768);
    tconv_k<<<dim3(48, 12), 256, 0, stream>>>(wfc  + (size_t)l * 768 * 3072, wfc_b,  768, 3072);
    tconv_k<<<dim3(12, 48), 256, 0, stream>>>(wfc2 + (size_t)l * 3072 * 768, wfc2_b, 3072, 768);

    ln_k<<<4096, 256, 0, stream>>>(x, l1g + l * 768, l1b + l * 768, h);
    gemm_k<0><<<dim3(18, 32), 256, 0, stream>>>(
        h, wqkv_b, bqkv + l * 2304, nullptr, qkv, 4096, 2304, 768);
    attn_k<<<dim3(16, 96), 256, 0, stream>>>(qkv, am, y);
    gemm_k<2><<<dim3(6, 32), 256, 0, stream>>>(
        y, wprj_b, bprj + l * 768, x, x, 4096, 768, 768);
    ln_k<<<4096, 256, 0, stream>>>(x, l2g + l * 768, l2b + l * 768, h);
    gemm_k<1><<<dim3(24, 32), 256, 0, stream>>>(
        h, wfc_b, bfc + l * 3072, nullptr, fc, 4096, 3072, 768);
    gemm_k<2><<<dim3(6, 32), 256, 0, stream>>>(
        fc, wfc2_b, bfc2 + l * 768, x, x, 4096, 768, 3072);
  }

  cast_k<<<3072, 256, 0, stream>>>(x, h);
  gemm_k<3><<<dim3(239, 32), 256, 0, stream>>>(
      h, we_b, nullptr, nullptr, d_out, 4096, 30522, 768);
}

// Round 3
// 3180.598 us; speedup vs baseline: 2.6334x; 2.3227x over previous
//
#include <hip/hip_runtime.h>
#include <hip/hip_bf16.h>

typedef unsigned short u16;
typedef __attribute__((ext_vector_type(4))) float f32x4;
typedef __attribute__((ext_vector_type(8))) __bf16 bf16x8;

#define DEV static __device__ __forceinline__

// ---------- helpers ----------
DEV float b2f(u16 v) { return __uint_as_float(((unsigned)v) << 16); }

DEV u16 f2b(float f) {  // round-to-nearest-even f32 -> bf16 bits
  unsigned u = __float_as_uint(f);
  return (u16)((u + 0x7fffu + ((u >> 16) & 1u)) >> 16);
}

DEV void gload16(const void* g, void* l) {
  // async global->LDS, 16B per lane; LDS dest is wave-uniform base + lane*16
  __builtin_amdgcn_global_load_lds(
      (__attribute__((address_space(1))) void*)g,
      (__attribute__((address_space(3))) void*)l, 16, 0, 0);
}

DEV float wave_sum(float v) {
  #pragma unroll
  for (int o = 32; o; o >>= 1) v += __shfl_xor(v, o, 64);
  return v;
}

// ---------- embeddings + LayerNorm (f32 out) ----------
__global__ __launch_bounds__(256)
void embed_ln_k(const int* __restrict__ ids, const int* __restrict__ tts,
                const float* __restrict__ we, const float* __restrict__ pe,
                const float* __restrict__ te, const float* __restrict__ g,
                const float* __restrict__ bb, float* __restrict__ x) {
  const int t = blockIdx.x;          // 0..4095 token index
  const int pos = t & 511;
  const int tid = threadIdx.x, lane = tid & 63, w = tid >> 6;
  const int id = ids[t], tt = tts[t];
  __shared__ float red[8];
  float e[3];
  #pragma unroll
  for (int k = 0; k < 3; k++) {
    int d = tid + k * 256;
    e[k] = we[(size_t)id * 768 + d] + pe[(size_t)pos * 768 + d] + te[(size_t)tt * 768 + d];
  }
  float s = wave_sum(e[0] + e[1] + e[2]);
  if (lane == 0) red[w] = s;
  __syncthreads();
  const float mean = (red[0] + red[1] + red[2] + red[3]) * (1.f / 768.f);
  float v2 = 0.f;
  #pragma unroll
  for (int k = 0; k < 3; k++) { float d = e[k] - mean; v2 += d * d; }
  v2 = wave_sum(v2);
  if (lane == 0) red[4 + w] = v2;
  __syncthreads();
  const float var = (red[4] + red[5] + red[6] + red[7]) * (1.f / 768.f);
  const float rstd = rsqrtf(var + 1e-5f);
  #pragma unroll
  for (int k = 0; k < 3; k++) {
    int d = tid + k * 256;
    x[(size_t)t * 768 + d] = (e[k] - mean) * rstd * g[d] + bb[d];
  }
}

// ---------- LayerNorm f32 -> bf16 ----------
__global__ __launch_bounds__(256)
void ln_k(const float* __restrict__ xin, const float* __restrict__ g,
          const float* __restrict__ bb, u16* __restrict__ out) {
  const int t = blockIdx.x;
  const int tid = threadIdx.x, lane = tid & 63, w = tid >> 6;
  __shared__ float red[8];
  float e[3];
  #pragma unroll
  for (int k = 0; k < 3; k++) e[k] = xin[(size_t)t * 768 + tid + k * 256];
  float s = wave_sum(e[0] + e[1] + e[2]);
  if (lane == 0) red[w] = s;
  __syncthreads();
  const float mean = (red[0] + red[1] + red[2] + red[3]) * (1.f / 768.f);
  float v2 = 0.f;
  #pragma unroll
  for (int k = 0; k < 3; k++) { float d = e[k] - mean; v2 += d * d; }
  v2 = wave_sum(v2);
  if (lane == 0) red[4 + w] = v2;
  __syncthreads();
  const float var = (red[4] + red[5] + red[6] + red[7]) * (1.f / 768.f);
  const float rstd = rsqrtf(var + 1e-5f);
  #pragma unroll
  for (int k = 0; k < 3; k++) {
    int d = tid + k * 256;
    out[(size_t)t * 768 + d] = f2b((e[k] - mean) * rstd * g[d] + bb[d]);
  }
}

// ---------- f32 -> bf16 cast (4 elems/thread) ----------
__global__ __launch_bounds__(256)
void cast_k(const float* __restrict__ xin, u16* __restrict__ out) {
  const int i = blockIdx.x * 256 + threadIdx.x;
  float4 v = ((const float4*)xin)[i];
  uint2 o;
  o.x = (unsigned)f2b(v.x) | ((unsigned)f2b(v.y) << 16);
  o.y = (unsigned)f2b(v.z) | ((unsigned)f2b(v.w) << 16);
  ((uint2*)out)[i] = o;
}

// ---------- word_emb f32[30522,768] -> bf16[30592,768], pad rows zeroed ----------
__global__ __launch_bounds__(256)
void wecast_k(const float* __restrict__ we, u16* __restrict__ out) {
  const int i = blockIdx.x * 256 + threadIdx.x;  // 8-elem chunk, 2,936,832 total
  const int row = i / 96, c8 = i % 96;
  uint2 o0 = make_uint2(0u, 0u), o1 = make_uint2(0u, 0u);
  if (row < 30522) {
    const float* src = we + (size_t)row * 768 + c8 * 8;
    float4 a = ((const float4*)src)[0];
    float4 b = ((const float4*)src)[1];
    o0.x = (unsigned)f2b(a.x) | ((unsigned)f2b(a.y) << 16);
    o0.y = (unsigned)f2b(a.z) | ((unsigned)f2b(a.w) << 16);
    o1.x = (unsigned)f2b(b.x) | ((unsigned)f2b(b.y) << 16);
    o1.y = (unsigned)f2b(b.z) | ((unsigned)f2b(b.w) << 16);
  }
  uint2* dst = (uint2*)(out + (size_t)i * 8);
  dst[0] = o0;
  dst[1] = o1;
}

// ---------- transpose-convert: W f32[K,N] -> Wt bf16[N,K] ----------
// grid (N/64, K/64), block 256
__global__ __launch_bounds__(256)
void tconv_k(const float* __restrict__ W, u16* __restrict__ Wt, int K, int N) {
  __shared__ u16 t[64][65];
  const int tid = threadIdx.x;
  const int n0 = blockIdx.x * 64, k0 = blockIdx.y * 64;
  const int kl = tid >> 4, nl4 = (tid & 15) * 4;
  #pragma unroll
  for (int i = 0; i < 4; i++) {
    float4 v = *(const float4*)(W + (size_t)(k0 + kl + i * 16) * N + n0 + nl4);
    t[nl4 + 0][kl + i * 16] = f2b(v.x);
    t[nl4 + 1][kl + i * 16] = f2b(v.y);
    t[nl4 + 2][kl + i * 16] = f2b(v.z);
    t[nl4 + 3][kl + i * 16] = f2b(v.w);
  }
  __syncthreads();
  const int nl = tid >> 2, kc = (tid & 3) * 16;
  unsigned wd[8];
  #pragma unroll
  for (int j = 0; j < 8; j++)
    wd[j] = (unsigned)t[nl][kc + 2 * j] | ((unsigned)t[nl][kc + 2 * j + 1] << 16);
  int4* dst = (int4*)(Wt + (size_t)(n0 + nl) * K + k0 + kc);
  dst[0] = make_int4((int)wd[0], (int)wd[1], (int)wd[2], (int)wd[3]);
  dst[1] = make_int4((int)wd[4], (int)wd[5], (int)wd[6], (int)wd[7]);
}

// ---------- GEMM: C[M,N] = epi(A_bf16[M,K] @ B_bf16[N,K]^T + bias) ----------
// EPI: 0 = store bf16; 1 = GELU -> bf16; 2 = resid_f32 + val -> f32; 3 = f32 store with N-guard.
template <int EPI>
__global__ __launch_bounds__(256)
void gemm_k(const u16* __restrict__ A, const u16* __restrict__ B,
            const float* __restrict__ bias, const float* __restrict__ resid,
            void* __restrict__ Cptr, int Mdim, int Ndim, int Kdim) {
  __shared__ __align__(16) u16 As[128 * 32];  // [row][k], k contiguous
  __shared__ __align__(16) u16 Bs[128 * 32];  // [col][k], k contiguous
  const int tid = threadIdx.x, lane = tid & 63, w = tid >> 6;
  const int wr = w >> 1, wc = w & 1, fr = lane & 15, fq = lane >> 4;
  const int n0 = blockIdx.x * 128, m0 = blockIdx.y * 128;
  f32x4 acc[4][4] = {};
  const int arow = w * 16 + (lane >> 2), akk = (lane & 3) * 8;

  for (int k0 = 0; k0 < Kdim; k0 += 32) {
    gload16(A + (size_t)(m0 + arow) * Kdim + k0 + akk, As + w * 512);
    gload16(A + (size_t)(m0 + 64 + arow) * Kdim + k0 + akk, As + 2048 + w * 512);
    gload16(B + (size_t)(n0 + arow) * Kdim + k0 + akk, Bs + w * 512);
    gload16(B + (size_t)(n0 + 64 + arow) * Kdim + k0 + akk, Bs + 2048 + w * 512);
    __syncthreads();
    bf16x8 af[4], bfv[4];
    #pragma unroll
    for (int m = 0; m < 4; m++)
      af[m] = *(const bf16x8*)(As + (wr * 64 + m * 16 + fr) * 32 + fq * 8);
    #pragma unroll
    for (int n = 0; n < 4; n++)
      bfv[n] = *(const bf16x8*)(Bs + (wc * 64 + n * 16 + fr) * 32 + fq * 8);
    #pragma unroll
    for (int m = 0; m < 4; m++)
      #pragma unroll
      for (int n = 0; n < 4; n++)
        acc[m][n] = __builtin_amdgcn_mfma_f32_16x16x32_bf16(af[m], bfv[n], acc[m][n], 0, 0, 0);
    __syncthreads();
  }

  #pragma unroll
  for (int m = 0; m < 4; m++) {
    const int row = m0 + wr * 64 + m * 16 + fq * 4;
    #pragma unroll
    for (int n = 0; n < 4; n++) {
      const int col = n0 + wc * 64 + n * 16 + fr;
      if (EPI == 3 && col >= Ndim) continue;
      const float bv = (bias != nullptr) ? bias[col] : 0.f;
      #pragma unroll
      for (int r = 0; r < 4; r++) {
        float v = acc[m][n][r] + bv;
        const size_t idx = (size_t)(row + r) * Ndim + col;
        if (EPI == 0) {
          ((u16*)Cptr)[idx] = f2b(v);
        } else if (EPI == 1) {
          float t = v;
          float gl = 0.5f * t * (1.f + tanhf(0.7978845608f * (t + 0.044715f * t * t * t)));
          ((u16*)Cptr)[idx] = f2b(gl);
        } else if (EPI == 2) {
          ((float*)Cptr)[idx] = resid[idx] + v;
        } else {
          ((float*)Cptr)[idx] = v;
        }
      }
    }
  }
}

// ---------- MFMA flash attention ----------
// grid (T/64=8, B*H=96), block 256 = 4 waves. Wave w handles q rows
// [q0 + w*16, q0 + w*16 + 16). KV tiles of 64 keys, double-buffered in LDS.
// All LDS tiles XOR-swizzled: 16B slot s of row r lives at slot s^(r&7).
__global__ __launch_bounds__(256)
void attn_mfma_k(const u16* __restrict__ qkv, const float* __restrict__ amask,
                 u16* __restrict__ y) {
  __shared__ __align__(16) u16 Ks[2][64 * 64];   // [key][dim]  16 KB
  __shared__ __align__(16) u16 Vt[2][64 * 64];   // [dim][key]  16 KB
  __shared__ __align__(16) u16 Ps[4][16 * 64];   // per-wave [q][key]  8 KB
  const int tid = threadIdx.x, lane = tid & 63, w = tid >> 6;
  const int bh = blockIdx.y, b = bh / 12, hh = bh % 12;
  const int q0 = blockIdx.x * 64;
  const u16* qb = qkv + (size_t)(b * 512) * 2304 + hh * 64;
  const u16* kb = qb + 768;
  const u16* vb = qb + 1536;
  const int fr = lane & 15, fq = lane >> 4;

  // Q fragments: A-frag rows fr, k-halves kh (once per block)
  bf16x8 af[2];
  {
    const u16* qrow = qb + (size_t)(q0 + w * 16 + fr) * 2304;
    af[0] = *(const bf16x8*)(qrow + fq * 8);
    af[1] = *(const bf16x8*)(qrow + 32 + fq * 8);
  }

  // stage K tile kt -> Ks[nb]: global_load_lds, source slot pre-swizzled
  auto stageK = [&](int kt, int nb) {
    const int r0 = lane >> 3, dc = lane & 7, s = dc ^ r0;
    #pragma unroll
    for (int p = 0; p < 2; p++) {
      const int i = w * 2 + p;
      gload16(kb + (size_t)(kt * 64 + i * 8 + r0) * 2304 + s * 8,
              (void*)&Ks[nb][i * 512]);
    }
  };
  // stage V tile kt -> Vt[nb] transposed: Vt[d][j], swizzled u16 idx j^((d&7)<<3)
  auto stageV = [&](int kt, int nb) {
    #pragma unroll
    for (int p = 0; p < 2; p++) {
      const int dc = w * 2 + p;
      int4 vd = *(const int4*)(vb + (size_t)(kt * 64 + lane) * 2304 + dc * 8);
      union { int4 v; u16 e[8]; } u; u.v = vd;
      #pragma unroll
      for (int ii = 0; ii < 8; ii++)
        Vt[nb][(dc * 8 + ii) * 64 + (lane ^ (ii << 3))] = u.e[ii];
    }
  };

  f32x4 O[4];
  #pragma unroll
  for (int nd = 0; nd < 4; nd++) O[nd] = f32x4{0.f, 0.f, 0.f, 0.f};
  float run_m[4], run_l[4];
  #pragma unroll
  for (int r = 0; r < 4; r++) { run_m[r] = -3.0e38f; run_l[r] = 0.f; }

  stageK(0, 0); stageV(0, 0);
  __syncthreads();
  int cur = 0;

  for (int kt = 0; kt < 8; kt++) {
    if (kt < 7) { stageK(kt + 1, cur ^ 1); stageV(kt + 1, cur ^ 1); }

    // ---- QK^T: S[q][j], C-layout col=key=fr', row=q=fq*4+r ----
    bf16x8 kf[4][2];
    #pragma unroll
    for (int n = 0; n < 4; n++)
      #pragma unroll
      for (int kh = 0; kh < 2; kh++)
        kf[n][kh] = *(const bf16x8*)(&Ks[cur][(n * 16 + fr) * 64 + ((kh * 4 + fq) ^ (fr & 7)) * 8]);
    f32x4 sacc[4];
    #pragma unroll
    for (int n = 0; n < 4; n++) sacc[n] = f32x4{0.f, 0.f, 0.f, 0.f};
    #pragma unroll
    for (int n = 0; n < 4; n++)
      #pragma unroll
      for (int kh = 0; kh < 2; kh++)
        sacc[n] = __builtin_amdgcn_mfma_f32_16x16x32_bf16(af[kh], kf[n][kh], sacc[n], 0, 0, 0);

    // ---- online softmax over this tile's 64 keys ----
    float mb[4];
    #pragma unroll
    for (int n = 0; n < 4; n++)
      mb[n] = (1.0f - amask[b * 512 + kt * 64 + n * 16 + fr]) * -10000.0f;
    float s[4][4];
    #pragma unroll
    for (int n = 0; n < 4; n++)
      #pragma unroll
      for (int r = 0; r < 4; r++) s[n][r] = sacc[n][r] * 0.125f + mb[n];
    float tm[4];
    #pragma unroll
    for (int r = 0; r < 4; r++) {
      tm[r] = fmaxf(fmaxf(s[0][r], s[1][r]), fmaxf(s[2][r], s[3][r]));
      #pragma unroll
      for (int o = 1; o < 16; o <<= 1) tm[r] = fmaxf(tm[r], __shfl_xor(tm[r], o, 64));
    }
    float al[4], ts[4];
    float p[4][4];
    #pragma unroll
    for (int r = 0; r < 4; r++) {
      float nm = fmaxf(run_m[r], tm[r]);
      al[r] = __expf(run_m[r] - nm);
      run_m[r] = nm;
      ts[r] = 0.f;
      #pragma unroll
      for (int n = 0; n < 4; n++) { p[n][r] = __expf(s[n][r] - nm); ts[r] += p[n][r]; }
      #pragma unroll
      for (int o = 1; o < 16; o <<= 1) ts[r] += __shfl_xor(ts[r], o, 64);
      run_l[r] = run_l[r] * al[r] + ts[r];
    }
    #pragma unroll
    for (int nd = 0; nd < 4; nd++)
      #pragma unroll
      for (int r = 0; r < 4; r++) O[nd][r] *= al[r];

    // ---- P (C-layout) -> Ps LDS (A-layout source), swizzled ----
    #pragma unroll
    for (int n = 0; n < 4; n++)
      #pragma unroll
      for (int r = 0; r < 4; r++) {
        const int q = fq * 4 + r, j = n * 16 + fr;
        Ps[w][q * 64 + (j ^ ((q & 7) << 3))] = f2b(p[n][r]);
      }
    asm volatile("s_waitcnt lgkmcnt(0)" ::: "memory");
    __builtin_amdgcn_sched_barrier(0);

    // ---- PV: O[q][d] += P @ V ----
    bf16x8 pa[2];
    #pragma unroll
    for (int kh = 0; kh < 2; kh++)
      pa[kh] = *(const bf16x8*)(&Ps[w][fr * 64 + ((kh * 4 + fq) ^ (fr & 7)) * 8]);
    #pragma unroll
    for (int nd = 0; nd < 4; nd++) {
      bf16x8 vf0 = *(const bf16x8*)(&Vt[cur][(nd * 16 + fr) * 64 + ((0 + fq) ^ (fr & 7)) * 8]);
      bf16x8 vf1 = *(const bf16x8*)(&Vt[cur][(nd * 16 + fr) * 64 + ((4 + fq) ^ (fr & 7)) * 8]);
      O[nd] = __builtin_amdgcn_mfma_f32_16x16x32_bf16(pa[0], vf0, O[nd], 0, 0, 0);
      O[nd] = __builtin_amdgcn_mfma_f32_16x16x32_bf16(pa[1], vf1, O[nd], 0, 0, 0);
    }
    __syncthreads();
    cur ^= 1;
  }

  // ---- epilogue: O /= l, write y ----
  float inv[4];
  #pragma unroll
  for (int r = 0; r < 4; r++) inv[r] = 1.0f / run_l[r];
  #pragma unroll
  for (int nd = 0; nd < 4; nd++)
    #pragma unroll
    for (int r = 0; r < 4; r++) {
      const int q = q0 + w * 16 + fq * 4 + r;
      y[(size_t)(b * 512 + q) * 768 + hh * 64 + nd * 16 + fr] = f2b(O[nd][r] * inv[r]);
    }
}

// ---------- launch ----------
extern "C" void kernel_launch(void* const* d_in, const int* in_sizes, int n_in,
                              void* d_out, int out_size, void* d_ws, size_t ws_size,
                              hipStream_t stream) {
  (void)in_sizes; (void)n_in; (void)out_size; (void)ws_size;
  const int*   ids  = (const int*)d_in[0];
  const int*   tts  = (const int*)d_in[1];
  const float* am   = (const float*)d_in[2];
  const float* we   = (const float*)d_in[3];
  const float* pe   = (const float*)d_in[4];
  const float* te   = (const float*)d_in[5];
  const float* eg   = (const float*)d_in[6];
  const float* eb   = (const float*)d_in[7];
  const float* l1g  = (const float*)d_in[8];
  const float* l1b  = (const float*)d_in[9];
  const float* wqkv = (const float*)d_in[10];
  const float* bqkv = (const float*)d_in[11];
  const float* wprj = (const float*)d_in[12];
  const float* bprj = (const float*)d_in[13];
  const float* l2g  = (const float*)d_in[14];
  const float* l2b  = (const float*)d_in[15];
  const float* wfc  = (const float*)d_in[16];
  const float* bfc  = (const float*)d_in[17];
  const float* wfc2 = (const float*)d_in[18];
  const float* bfc2 = (const float*)d_in[19];

  char* ws = (char*)d_ws;
  float* x   = (float*)ws;                      // 12,582,912 B  activations f32
  u16*  h    = (u16*)(ws + 12582912);           //  6,291,456 B  LN output bf16
  u16*  qkv  = (u16*)(ws + 18874368);           // 18,874,368 B
  u16*  y    = (u16*)(ws + 37748736);           //  6,291,456 B
  u16*  fc   = (u16*)(ws + 18874368);           // aliases qkv+y (dead by then)
  // bf16 weight staging (reused each layer)
  u16*  wqkv_b = (u16*)(ws + 44040192);         //  3,538,944 B  [2304,768]
  u16*  wprj_b = (u16*)(ws + 47579136);         //  1,179,648 B  [768,768]
  u16*  wfc_b  = (u16*)(ws + 48758784);         //  4,718,592 B  [3072,768]
  u16*  wfc2_b = (u16*)(ws + 53477376);         //  4,718,592 B  [768,3072]
  u16*  we_b   = (u16*)(ws + 58195968);         // 46,989,312 B  [30592,768] zero-padded
  // total ws use: 105,185,280 B

  wecast_k<<<11472, 256, 0, stream>>>(we, we_b);
  embed_ln_k<<<4096, 256, 0, stream>>>(ids, tts, we, pe, te, eg, eb, x);

  for (int l = 0; l < 12; l++) {
    tconv_k<<<dim3(36, 12), 256, 0, stream>>>(wqkv + (size_t)l * 768 * 2304, wqkv_b, 768, 2304);
    tconv_k<<<dim3(12, 12), 256, 0, stream>>>(wprj + (size_t)l * 768 * 768,  wprj_b, 768, 768);
    tconv_k<<<dim3(48, 12), 256, 0, stream>>>(wfc  + (size_t)l * 768 * 3072, wfc_b,  768, 3072);
    tconv_k<<<dim3(12, 48), 256, 0, stream>>>(wfc2 + (size_t)l * 3072 * 768, wfc2_b, 3072, 768);

    ln_k<<<4096, 256, 0, stream>>>(x, l1g + l * 768, l1b + l * 768, h);
    gemm_k<0><<<dim3(18, 32), 256, 0, stream>>>(
        h, wqkv_b, bqkv + l * 2304, nullptr, qkv, 4096, 2304, 768);
    attn_mfma_k<<<dim3(8, 96), 256, 0, stream>>>(qkv, am, y);
    gemm_k<2><<<dim3(6, 32), 256, 0, stream>>>(
        y, wprj_b, bprj + l * 768, x, x, 4096, 768, 768);
    ln_k<<<4096, 256, 0, stream>>>(x, l2g + l * 768, l2b + l * 768, h);
    gemm_k<1><<<dim3(24, 32), 256, 0, stream>>>(
        h, wfc_b, bfc + l * 3072, nullptr, fc, 4096, 3072, 768);
    gemm_k<2><<<dim3(6, 32), 256, 0, stream>>>(
        fc, wfc2_b, bfc2 + l * 768, x, x, 4096, 768, 3072);
  }

  cast_k<<<3072, 256, 0, stream>>>(x, h);
  gemm_k<3><<<dim3(239, 32), 256, 0, stream>>>(
      h, we_b, nullptr, nullptr, d_out, 4096, 30522, 768);
}

// Round 4
// 2911.008 us; speedup vs baseline: 2.8773x; 1.0926x over previous
//
#include <hip/hip_runtime.h>
#include <hip/hip_bf16.h>

typedef unsigned short u16;
typedef __attribute__((ext_vector_type(4))) float f32x4;
typedef __attribute__((ext_vector_type(8))) __bf16 bf16x8;

#define DEV static __device__ __forceinline__

// ---------- helpers ----------
DEV float b2f(u16 v) { return __uint_as_float(((unsigned)v) << 16); }

DEV u16 f2b(float f) {  // round-to-nearest-even f32 -> bf16 bits
  unsigned u = __float_as_uint(f);
  return (u16)((u + 0x7fffu + ((u >> 16) & 1u)) >> 16);
}

DEV void gload16(const void* g, void* l) {
  // async global->LDS, 16B per lane; LDS dest is wave-uniform base + lane*16
  __builtin_amdgcn_global_load_lds(
      (__attribute__((address_space(1))) void*)g,
      (__attribute__((address_space(3))) void*)l, 16, 0, 0);
}

DEV float wave_sum(float v) {
  #pragma unroll
  for (int o = 32; o; o >>= 1) v += __shfl_xor(v, o, 64);
  return v;
}

// ---------- embeddings + LayerNorm (f32 out) ----------
__global__ __launch_bounds__(256)
void embed_ln_k(const int* __restrict__ ids, const int* __restrict__ tts,
                const float* __restrict__ we, const float* __restrict__ pe,
                const float* __restrict__ te, const float* __restrict__ g,
                const float* __restrict__ bb, float* __restrict__ x) {
  const int t = blockIdx.x;          // 0..4095 token index
  const int pos = t & 511;
  const int tid = threadIdx.x, lane = tid & 63, w = tid >> 6;
  const int id = ids[t], tt = tts[t];
  __shared__ float red[8];
  float e[3];
  #pragma unroll
  for (int k = 0; k < 3; k++) {
    int d = tid + k * 256;
    e[k] = we[(size_t)id * 768 + d] + pe[(size_t)pos * 768 + d] + te[(size_t)tt * 768 + d];
  }
  float s = wave_sum(e[0] + e[1] + e[2]);
  if (lane == 0) red[w] = s;
  __syncthreads();
  const float mean = (red[0] + red[1] + red[2] + red[3]) * (1.f / 768.f);
  float v2 = 0.f;
  #pragma unroll
  for (int k = 0; k < 3; k++) { float d = e[k] - mean; v2 += d * d; }
  v2 = wave_sum(v2);
  if (lane == 0) red[4 + w] = v2;
  __syncthreads();
  const float var = (red[4] + red[5] + red[6] + red[7]) * (1.f / 768.f);
  const float rstd = rsqrtf(var + 1e-5f);
  #pragma unroll
  for (int k = 0; k < 3; k++) {
    int d = tid + k * 256;
    x[(size_t)t * 768 + d] = (e[k] - mean) * rstd * g[d] + bb[d];
  }
}

// ---------- LayerNorm f32 -> bf16 ----------
__global__ __launch_bounds__(256)
void ln_k(const float* __restrict__ xin, const float* __restrict__ g,
          const float* __restrict__ bb, u16* __restrict__ out) {
  const int t = blockIdx.x;
  const int tid = threadIdx.x, lane = tid & 63, w = tid >> 6;
  __shared__ float red[8];
  float e[3];
  #pragma unroll
  for (int k = 0; k < 3; k++) e[k] = xin[(size_t)t * 768 + tid + k * 256];
  float s = wave_sum(e[0] + e[1] + e[2]);
  if (lane == 0) red[w] = s;
  __syncthreads();
  const float mean = (red[0] + red[1] + red[2] + red[3]) * (1.f / 768.f);
  float v2 = 0.f;
  #pragma unroll
  for (int k = 0; k < 3; k++) { float d = e[k] - mean; v2 += d * d; }
  v2 = wave_sum(v2);
  if (lane == 0) red[4 + w] = v2;
  __syncthreads();
  const float var = (red[4] + red[5] + red[6] + red[7]) * (1.f / 768.f);
  const float rstd = rsqrtf(var + 1e-5f);
  #pragma unroll
  for (int k = 0; k < 3; k++) {
    int d = tid + k * 256;
    out[(size_t)t * 768 + d] = f2b((e[k] - mean) * rstd * g[d] + bb[d]);
  }
}

// ---------- f32 -> bf16 cast (4 elems/thread) ----------
__global__ __launch_bounds__(256)
void cast_k(const float* __restrict__ xin, u16* __restrict__ out) {
  const int i = blockIdx.x * 256 + threadIdx.x;
  float4 v = ((const float4*)xin)[i];
  uint2 o;
  o.x = (unsigned)f2b(v.x) | ((unsigned)f2b(v.y) << 16);
  o.y = (unsigned)f2b(v.z) | ((unsigned)f2b(v.w) << 16);
  ((uint2*)out)[i] = o;
}

// ---------- word_emb f32[30522,768] -> bf16[30592,768], pad rows zeroed ----------
__global__ __launch_bounds__(256)
void wecast_k(const float* __restrict__ we, u16* __restrict__ out) {
  const int i = blockIdx.x * 256 + threadIdx.x;  // 8-elem chunk, 2,936,832 total
  const int row = i / 96, c8 = i % 96;
  uint2 o0 = make_uint2(0u, 0u), o1 = make_uint2(0u, 0u);
  if (row < 30522) {
    const float* src = we + (size_t)row * 768 + c8 * 8;
    float4 a = ((const float4*)src)[0];
    float4 b = ((const float4*)src)[1];
    o0.x = (unsigned)f2b(a.x) | ((unsigned)f2b(a.y) << 16);
    o0.y = (unsigned)f2b(a.z) | ((unsigned)f2b(a.w) << 16);
    o1.x = (unsigned)f2b(b.x) | ((unsigned)f2b(b.y) << 16);
    o1.y = (unsigned)f2b(b.z) | ((unsigned)f2b(b.w) << 16);
  }
  uint2* dst = (uint2*)(out + (size_t)i * 8);
  dst[0] = o0;
  dst[1] = o1;
}

// ---------- transpose-convert: W f32[K,N] -> Wt bf16[N,K] ----------
// grid (N/64, K/64), block 256
__global__ __launch_bounds__(256)
void tconv_k(const float* __restrict__ W, u16* __restrict__ Wt, int K, int N) {
  __shared__ u16 t[64][65];
  const int tid = threadIdx.x;
  const int n0 = blockIdx.x * 64, k0 = blockIdx.y * 64;
  const int kl = tid >> 4, nl4 = (tid & 15) * 4;
  #pragma unroll
  for (int i = 0; i < 4; i++) {
    float4 v = *(const float4*)(W + (size_t)(k0 + kl + i * 16) * N + n0 + nl4);
    t[nl4 + 0][kl + i * 16] = f2b(v.x);
    t[nl4 + 1][kl + i * 16] = f2b(v.y);
    t[nl4 + 2][kl + i * 16] = f2b(v.z);
    t[nl4 + 3][kl + i * 16] = f2b(v.w);
  }
  __syncthreads();
  const int nl = tid >> 2, kc = (tid & 3) * 16;
  unsigned wd[8];
  #pragma unroll
  for (int j = 0; j < 8; j++)
    wd[j] = (unsigned)t[nl][kc + 2 * j] | ((unsigned)t[nl][kc + 2 * j + 1] << 16);
  int4* dst = (int4*)(Wt + (size_t)(n0 + nl) * K + k0 + kc);
  dst[0] = make_int4((int)wd[0], (int)wd[1], (int)wd[2], (int)wd[3]);
  dst[1] = make_int4((int)wd[4], (int)wd[5], (int)wd[6], (int)wd[7]);
}

// ---------- GEMM: C[M,N] = epi(A_bf16[M,K] @ B_bf16[N,K]^T + bias) ----------
// 1-D grid of Mblk*Nblk blocks, XCD-chunk swizzled (nwg % 8 == 0 required).
// MFAST=1: M-fastest tile decode (B-panel L2 reuse, for huge-N logits GEMM).
// MFAST=0: N-fastest (A-panel reuse; weights L2-resident).
// BK=64: two BK=32 LDS sub-tiles staged per barrier pair (halved barrier rate).
// EPI: 0 = bf16; 1 = GELU -> bf16; 2 = resid_f32 + v -> f32; 3 = f32, N-guard.
template <int EPI, int MFAST>
__global__ __launch_bounds__(256)
void gemm_k(const u16* __restrict__ A, const u16* __restrict__ B,
            const float* __restrict__ bias, const float* __restrict__ resid,
            void* __restrict__ Cptr, int Ndim, int Kdim, int Nblk) {
  __shared__ __align__(16) u16 As[2][128 * 32];  // [khalf][row][k]
  __shared__ __align__(16) u16 Bs[2][128 * 32];
  const int tid = threadIdx.x, lane = tid & 63, w = tid >> 6;
  const int wr = w >> 1, wc = w & 1, fr = lane & 15, fq = lane >> 4;

  // XCD-chunk swizzle: dispatch-order bid -> contiguous tile range per XCD
  const int nwg = gridDim.x, chunk = nwg >> 3;
  const int tile = (blockIdx.x & 7) * chunk + (blockIdx.x >> 3);
  int mb, nb;
  if (MFAST) { const int Mblk = nwg / Nblk; mb = tile % Mblk; nb = tile / Mblk; }
  else       { nb = tile % Nblk; mb = tile / Nblk; }
  const int n0 = nb * 128, m0 = mb * 128;

  f32x4 acc[4][4] = {};
  const int arow = w * 16 + (lane >> 2), akk = (lane & 3) * 8;

  for (int k0 = 0; k0 < Kdim; k0 += 64) {
    #pragma unroll
    for (int kh = 0; kh < 2; kh++) {
      const int kk = k0 + kh * 32 + akk;
      gload16(A + (size_t)(m0 + arow) * Kdim + kk,      &As[kh][w * 512]);
      gload16(A + (size_t)(m0 + 64 + arow) * Kdim + kk, &As[kh][2048 + w * 512]);
      gload16(B + (size_t)(n0 + arow) * Kdim + kk,      &Bs[kh][w * 512]);
      gload16(B + (size_t)(n0 + 64 + arow) * Kdim + kk, &Bs[kh][2048 + w * 512]);
    }
    __syncthreads();
    #pragma unroll
    for (int kh = 0; kh < 2; kh++) {
      bf16x8 af[4], bfv[4];
      #pragma unroll
      for (int m = 0; m < 4; m++)
        af[m] = *(const bf16x8*)(&As[kh][(wr * 64 + m * 16 + fr) * 32 + fq * 8]);
      #pragma unroll
      for (int n = 0; n < 4; n++)
        bfv[n] = *(const bf16x8*)(&Bs[kh][(wc * 64 + n * 16 + fr) * 32 + fq * 8]);
      #pragma unroll
      for (int m = 0; m < 4; m++)
        #pragma unroll
        for (int n = 0; n < 4; n++)
          acc[m][n] = __builtin_amdgcn_mfma_f32_16x16x32_bf16(af[m], bfv[n], acc[m][n], 0, 0, 0);
    }
    __syncthreads();
  }

  #pragma unroll
  for (int m = 0; m < 4; m++) {
    const int row = m0 + wr * 64 + m * 16 + fq * 4;
    #pragma unroll
    for (int n = 0; n < 4; n++) {
      const int col = n0 + wc * 64 + n * 16 + fr;
      if (EPI == 3 && col >= Ndim) continue;
      const float bv = (bias != nullptr) ? bias[col] : 0.f;
      #pragma unroll
      for (int r = 0; r < 4; r++) {
        float v = acc[m][n][r] + bv;
        const size_t idx = (size_t)(row + r) * Ndim + col;
        if (EPI == 0) {
          ((u16*)Cptr)[idx] = f2b(v);
        } else if (EPI == 1) {
          float t = v;
          float gl = 0.5f * t * (1.f + tanhf(0.7978845608f * (t + 0.044715f * t * t * t)));
          ((u16*)Cptr)[idx] = f2b(gl);
        } else if (EPI == 2) {
          ((float*)Cptr)[idx] = resid[idx] + v;
        } else {
          ((float*)Cptr)[idx] = v;
        }
      }
    }
  }
}

// ---------- MFMA flash attention ----------
// grid (T/64=8, B*H=96), block 256 = 4 waves. Wave w handles q rows
// [q0 + w*16, q0 + w*16 + 16). KV tiles of 64 keys, double-buffered in LDS.
// All LDS tiles XOR-swizzled: 16B slot s of row r lives at slot s^(r&7).
__global__ __launch_bounds__(256)
void attn_mfma_k(const u16* __restrict__ qkv, const float* __restrict__ amask,
                 u16* __restrict__ y) {
  __shared__ __align__(16) u16 Ks[2][64 * 64];   // [key][dim]  16 KB
  __shared__ __align__(16) u16 Vt[2][64 * 64];   // [dim][key]  16 KB
  __shared__ __align__(16) u16 Ps[4][16 * 64];   // per-wave [q][key]  8 KB
  const int tid = threadIdx.x, lane = tid & 63, w = tid >> 6;
  const int bh = blockIdx.y, b = bh / 12, hh = bh % 12;
  const int q0 = blockIdx.x * 64;
  const u16* qb = qkv + (size_t)(b * 512) * 2304 + hh * 64;
  const u16* kb = qb + 768;
  const u16* vb = qb + 1536;
  const int fr = lane & 15, fq = lane >> 4;

  // Q fragments: A-frag rows fr, k-halves kh (once per block)
  bf16x8 af[2];
  {
    const u16* qrow = qb + (size_t)(q0 + w * 16 + fr) * 2304;
    af[0] = *(const bf16x8*)(qrow + fq * 8);
    af[1] = *(const bf16x8*)(qrow + 32 + fq * 8);
  }

  // stage K tile kt -> Ks[nb]: global_load_lds, source slot pre-swizzled
  auto stageK = [&](int kt, int nb) {
    const int r0 = lane >> 3, dc = lane & 7, s = dc ^ r0;
    #pragma unroll
    for (int p = 0; p < 2; p++) {
      const int i = w * 2 + p;
      gload16(kb + (size_t)(kt * 64 + i * 8 + r0) * 2304 + s * 8,
              (void*)&Ks[nb][i * 512]);
    }
  };
  // stage V tile kt -> Vt[nb] transposed: Vt[d][j], swizzled u16 idx j^((d&7)<<3)
  auto stageV = [&](int kt, int nb) {
    #pragma unroll
    for (int p = 0; p < 2; p++) {
      const int dc = w * 2 + p;
      int4 vd = *(const int4*)(vb + (size_t)(kt * 64 + lane) * 2304 + dc * 8);
      union { int4 v; u16 e[8]; } u; u.v = vd;
      #pragma unroll
      for (int ii = 0; ii < 8; ii++)
        Vt[nb][(dc * 8 + ii) * 64 + (lane ^ (ii << 3))] = u.e[ii];
    }
  };

  f32x4 O[4];
  #pragma unroll
  for (int nd = 0; nd < 4; nd++) O[nd] = f32x4{0.f, 0.f, 0.f, 0.f};
  float run_m[4], run_l[4];
  #pragma unroll
  for (int r = 0; r < 4; r++) { run_m[r] = -3.0e38f; run_l[r] = 0.f; }

  stageK(0, 0); stageV(0, 0);
  __syncthreads();
  int cur = 0;

  for (int kt = 0; kt < 8; kt++) {
    if (kt < 7) { stageK(kt + 1, cur ^ 1); stageV(kt + 1, cur ^ 1); }

    // ---- QK^T: S[q][j], C-layout col=key=fr', row=q=fq*4+r ----
    bf16x8 kf[4][2];
    #pragma unroll
    for (int n = 0; n < 4; n++)
      #pragma unroll
      for (int kh = 0; kh < 2; kh++)
        kf[n][kh] = *(const bf16x8*)(&Ks[cur][(n * 16 + fr) * 64 + ((kh * 4 + fq) ^ (fr & 7)) * 8]);
    f32x4 sacc[4];
    #pragma unroll
    for (int n = 0; n < 4; n++) sacc[n] = f32x4{0.f, 0.f, 0.f, 0.f};
    #pragma unroll
    for (int n = 0; n < 4; n++)
      #pragma unroll
      for (int kh = 0; kh < 2; kh++)
        sacc[n] = __builtin_amdgcn_mfma_f32_16x16x32_bf16(af[kh], kf[n][kh], sacc[n], 0, 0, 0);

    // ---- online softmax over this tile's 64 keys ----
    float mb[4];
    #pragma unroll
    for (int n = 0; n < 4; n++)
      mb[n] = (1.0f - amask[b * 512 + kt * 64 + n * 16 + fr]) * -10000.0f;
    float s[4][4];
    #pragma unroll
    for (int n = 0; n < 4; n++)
      #pragma unroll
      for (int r = 0; r < 4; r++) s[n][r] = sacc[n][r] * 0.125f + mb[n];
    float tm[4];
    #pragma unroll
    for (int r = 0; r < 4; r++) {
      tm[r] = fmaxf(fmaxf(s[0][r], s[1][r]), fmaxf(s[2][r], s[3][r]));
      #pragma unroll
      for (int o = 1; o < 16; o <<= 1) tm[r] = fmaxf(tm[r], __shfl_xor(tm[r], o, 64));
    }
    float al[4], ts[4];
    float p[4][4];
    #pragma unroll
    for (int r = 0; r < 4; r++) {
      float nm = fmaxf(run_m[r], tm[r]);
      al[r] = __expf(run_m[r] - nm);
      run_m[r] = nm;
      ts[r] = 0.f;
      #pragma unroll
      for (int n = 0; n < 4; n++) { p[n][r] = __expf(s[n][r] - nm); ts[r] += p[n][r]; }
      #pragma unroll
      for (int o = 1; o < 16; o <<= 1) ts[r] += __shfl_xor(ts[r], o, 64);
      run_l[r] = run_l[r] * al[r] + ts[r];
    }
    #pragma unroll
    for (int nd = 0; nd < 4; nd++)
      #pragma unroll
      for (int r = 0; r < 4; r++) O[nd][r] *= al[r];

    // ---- P (C-layout) -> Ps LDS (A-layout source), swizzled ----
    #pragma unroll
    for (int n = 0; n < 4; n++)
      #pragma unroll
      for (int r = 0; r < 4; r++) {
        const int q = fq * 4 + r, j = n * 16 + fr;
        Ps[w][q * 64 + (j ^ ((q & 7) << 3))] = f2b(p[n][r]);
      }
    asm volatile("s_waitcnt lgkmcnt(0)" ::: "memory");
    __builtin_amdgcn_sched_barrier(0);

    // ---- PV: O[q][d] += P @ V ----
    bf16x8 pa[2];
    #pragma unroll
    for (int kh = 0; kh < 2; kh++)
      pa[kh] = *(const bf16x8*)(&Ps[w][fr * 64 + ((kh * 4 + fq) ^ (fr & 7)) * 8]);
    #pragma unroll
    for (int nd = 0; nd < 4; nd++) {
      bf16x8 vf0 = *(const bf16x8*)(&Vt[cur][(nd * 16 + fr) * 64 + ((0 + fq) ^ (fr & 7)) * 8]);
      bf16x8 vf1 = *(const bf16x8*)(&Vt[cur][(nd * 16 + fr) * 64 + ((4 + fq) ^ (fr & 7)) * 8]);
      O[nd] = __builtin_amdgcn_mfma_f32_16x16x32_bf16(pa[0], vf0, O[nd], 0, 0, 0);
      O[nd] = __builtin_amdgcn_mfma_f32_16x16x32_bf16(pa[1], vf1, O[nd], 0, 0, 0);
    }
    __syncthreads();
    cur ^= 1;
  }

  // ---- epilogue: O /= l, write y ----
  float inv[4];
  #pragma unroll
  for (int r = 0; r < 4; r++) inv[r] = 1.0f / run_l[r];
  #pragma unroll
  for (int nd = 0; nd < 4; nd++)
    #pragma unroll
    for (int r = 0; r < 4; r++) {
      const int q = q0 + w * 16 + fq * 4 + r;
      y[(size_t)(b * 512 + q) * 768 + hh * 64 + nd * 16 + fr] = f2b(O[nd][r] * inv[r]);
    }
}

// ---------- launch ----------
extern "C" void kernel_launch(void* const* d_in, const int* in_sizes, int n_in,
                              void* d_out, int out_size, void* d_ws, size_t ws_size,
                              hipStream_t stream) {
  (void)in_sizes; (void)n_in; (void)out_size; (void)ws_size;
  const int*   ids  = (const int*)d_in[0];
  const int*   tts  = (const int*)d_in[1];
  const float* am   = (const float*)d_in[2];
  const float* we   = (const float*)d_in[3];
  const float* pe   = (const float*)d_in[4];
  const float* te   = (const float*)d_in[5];
  const float* eg   = (const float*)d_in[6];
  const float* eb   = (const float*)d_in[7];
  const float* l1g  = (const float*)d_in[8];
  const float* l1b  = (const float*)d_in[9];
  const float* wqkv = (const float*)d_in[10];
  const float* bqkv = (const float*)d_in[11];
  const float* wprj = (const float*)d_in[12];
  const float* bprj = (const float*)d_in[13];
  const float* l2g  = (const float*)d_in[14];
  const float* l2b  = (const float*)d_in[15];
  const float* wfc  = (const float*)d_in[16];
  const float* bfc  = (const float*)d_in[17];
  const float* wfc2 = (const float*)d_in[18];
  const float* bfc2 = (const float*)d_in[19];

  char* ws = (char*)d_ws;
  float* x   = (float*)ws;                      // 12,582,912 B  activations f32
  u16*  h    = (u16*)(ws + 12582912);           //  6,291,456 B  LN output bf16
  u16*  qkv  = (u16*)(ws + 18874368);           // 18,874,368 B
  u16*  y    = (u16*)(ws + 37748736);           //  6,291,456 B
  u16*  fc   = (u16*)(ws + 18874368);           // aliases qkv+y (dead by then)
  // bf16 weight staging (reused each layer)
  u16*  wqkv_b = (u16*)(ws + 44040192);         //  3,538,944 B  [2304,768]
  u16*  wprj_b = (u16*)(ws + 47579136);         //  1,179,648 B  [768,768]
  u16*  wfc_b  = (u16*)(ws + 48758784);         //  4,718,592 B  [3072,768]
  u16*  wfc2_b = (u16*)(ws + 53477376);         //  4,718,592 B  [768,3072]
  u16*  we_b   = (u16*)(ws + 58195968);         // 46,989,312 B  [30592,768] zero-padded
  // total ws use: 105,185,280 B

  wecast_k<<<11472, 256, 0, stream>>>(we, we_b);
  embed_ln_k<<<4096, 256, 0, stream>>>(ids, tts, we, pe, te, eg, eb, x);

  for (int l = 0; l < 12; l++) {
    tconv_k<<<dim3(36, 12), 256, 0, stream>>>(wqkv + (size_t)l * 768 * 2304, wqkv_b, 768, 2304);
    tconv_k<<<dim3(12, 12), 256, 0, stream>>>(wprj + (size_t)l * 768 * 768,  wprj_b, 768, 768);
    tconv_k<<<dim3(48, 12), 256, 0, stream>>>(wfc  + (size_t)l * 768 * 3072, wfc_b,  768, 3072);
    tconv_k<<<dim3(12, 48), 256, 0, stream>>>(wfc2 + (size_t)l * 3072 * 768, wfc2_b, 3072, 768);

    ln_k<<<4096, 256, 0, stream>>>(x, l1g + l * 768, l1b + l * 768, h);
    gemm_k<0, 0><<<576, 256, 0, stream>>>(
        h, wqkv_b, bqkv + l * 2304, nullptr, qkv, 2304, 768, 18);
    attn_mfma_k<<<dim3(8, 96), 256, 0, stream>>>(qkv, am, y);
    gemm_k<2, 0><<<192, 256, 0, stream>>>(
        y, wprj_b, bprj + l * 768, x, x, 768, 768, 6);
    ln_k<<<4096, 256, 0, stream>>>(x, l2g + l * 768, l2b + l * 768, h);
    gemm_k<1, 0><<<768, 256, 0, stream>>>(
        h, wfc_b, bfc + l * 3072, nullptr, fc, 3072, 768, 24);
    gemm_k<2, 0><<<192, 256, 0, stream>>>(
        fc, wfc2_b, bfc2 + l * 768, x, x, 768, 3072, 6);
  }

  cast_k<<<3072, 256, 0, stream>>>(x, h);
  gemm_k<3, 1><<<7648, 256, 0, stream>>>(
      h, we_b, nullptr, nullptr, d_out, 30522, 768, 239);
}